// Round 1
// baseline (958.724 us; speedup 1.0000x reference)
//
#include <hip/hip_runtime.h>

// incidence_matrix_learn on MI355X.
// Key algebraic simplifications (see analysis):
//  - top-k mask is a no-op: adj_bin = (softmax(relu(3*a)) > 0.5), at most one per row
//  - P[n,m] = (label[n] == label[m] != -1) && n != m   (label = the >0.5 hyperedge)
//  - logsumexp row max is the diagonal sim = 1/TAU = 10 -> fixed-shift LSE
//
// ws layout: nhat0 (bf16, 64*640*512) | nhat1 (bf16, 64*384*512) |
//            labels0[640] labels1[384] cnt0[640] cnt1[384] valid[2] | acc[2] (float)

#define DDIM 512
#define BATCH 64

__device__ __forceinline__ unsigned short f2bf(float f) {
  unsigned int u = __float_as_uint(f);
  u += 0x7fffu + ((u >> 16) & 1u);   // RNE
  return (unsigned short)(u >> 16);
}

__global__ void init_kernel(float* __restrict__ acc) {
  acc[0] = 0.f;
  acc[1] = 0.f;
}

// One block per node row n. Computes a[h] = enod[n] . ehy[h], relu*3, softmax,
// writes binary incidence row to out_adj and the label (argmax if >0.5 else -1).
__global__ __launch_bounds__(128) void adj_kernel(
    const float* __restrict__ enod, const float* __restrict__ ehy,
    int N, int H, float* __restrict__ out_adj, int* __restrict__ labels) {
  const int n = blockIdx.x;
  const int t = threadIdx.x;
  __shared__ float erow[DDIM];
  __shared__ float red[128];
  __shared__ int lab;
  ((float4*)erow)[t] = ((const float4*)(enod + (size_t)n * DDIM))[t];
  if (t == 0) lab = -1;
  __syncthreads();
  float v = 0.f;
  if (t < H) {
    const float4* hr = (const float4*)(ehy + (size_t)t * DDIM);
    float a = 0.f;
    #pragma unroll 8
    for (int d = 0; d < DDIM / 4; ++d) {
      float4 h = hr[d];
      float4 e = ((const float4*)erow)[d];
      a = fmaf(h.x, e.x, a); a = fmaf(h.y, e.y, a);
      a = fmaf(h.z, e.z, a); a = fmaf(h.w, e.w, a);
    }
    v = fmaxf(0.f, 3.0f * a);   // relu(alpha * a), >= 0
  }
  // block max (idle threads contribute 0; safe since max >= 0 always)
  red[t] = v;
  __syncthreads();
  for (int s = 64; s > 0; s >>= 1) {
    if (t < s) red[t] = fmaxf(red[t], red[t + s]);
    __syncthreads();
  }
  const float mx = red[0];
  __syncthreads();
  const float e = (t < H) ? __expf(v - mx) : 0.f;
  red[t] = e;
  __syncthreads();
  for (int s = 64; s > 0; s >>= 1) {
    if (t < s) red[t] += red[t + s];
    __syncthreads();
  }
  const float sum = red[0];
  if (t < H) {
    const float adj = e / sum;
    const float bin = (adj > 0.5f) ? 1.0f : 0.0f;
    out_adj[(size_t)n * H + t] = bin;
    if (bin > 0.f) lab = t;   // at most one thread: softmax row sums to 1
  }
  __syncthreads();
  if (t == 0) labels[n] = lab;
}

// Single block: cnt[n] = #{m != n : label[m] == label[n] != -1}; valid count.
__global__ __launch_bounds__(256) void cnt_kernel(
    const int* __restrict__ labels, int N, int* __restrict__ cnt,
    int* __restrict__ validcnt) {
  __shared__ int lab[640];
  __shared__ int vc;
  const int t = threadIdx.x;
  if (t == 0) vc = 0;
  for (int i = t; i < N; i += 256) lab[i] = labels[i];
  __syncthreads();
  for (int i = t; i < N; i += 256) {
    int c = 0;
    const int ln = lab[i];
    if (ln >= 0) {
      for (int m = 0; m < N; ++m) c += (m != i && lab[m] == ln) ? 1 : 0;
    }
    cnt[i] = c;
    if (c > 0) atomicAdd(&vc, 1);
  }
  __syncthreads();
  if (t == 0) *validcnt = vc;
}

// One block per (b, n): L2-normalize the node vector, store bf16 into nhat.
__global__ __launch_bounds__(128) void normalize_kernel(
    const float* __restrict__ x, const float* __restrict__ w,
    int L, int N, unsigned short* __restrict__ nhat) {
  const int bid = blockIdx.x;
  const int b = bid / N;
  const int n = bid - b * N;
  const int t = threadIdx.x;
  const float* src = (n < L) ? (x + ((size_t)b * L + n) * DDIM)
                             : (w + (size_t)(n - L) * DDIM);
  const float4 v = ((const float4*)src)[t];
  float ss = v.x * v.x + v.y * v.y + v.z * v.z + v.w * v.w;
  #pragma unroll
  for (int off = 32; off > 0; off >>= 1) ss += __shfl_down(ss, off);
  __shared__ float s2[2];
  if ((t & 63) == 0) s2[t >> 6] = ss;
  __syncthreads();
  const float rinv = 1.0f / fmaxf(sqrtf(s2[0] + s2[1]), 1e-12f);
  ushort4 o;
  o.x = f2bf(v.x * rinv);
  o.y = f2bf(v.y * rinv);
  o.z = f2bf(v.z * rinv);
  o.w = f2bf(v.w * rinv);
  ((ushort4*)(nhat + ((size_t)b * N + n) * DDIM))[t] = o;
}

__device__ __forceinline__ void store8(float (*S)[64], int kb, int nl, uint4 v) {
  S[kb + 0][nl] = __uint_as_float(v.x << 16);
  S[kb + 1][nl] = __uint_as_float(v.x & 0xffff0000u);
  S[kb + 2][nl] = __uint_as_float(v.y << 16);
  S[kb + 3][nl] = __uint_as_float(v.y & 0xffff0000u);
  S[kb + 4][nl] = __uint_as_float(v.z << 16);
  S[kb + 5][nl] = __uint_as_float(v.z & 0xffff0000u);
  S[kb + 6][nl] = __uint_as_float(v.w << 16);
  S[kb + 7][nl] = __uint_as_float(v.w & 0xffff0000u);
}

// Main kernel: per (b, 64-row n-tile), loop all 64-col m-tiles; 4x4 acc/thread.
// Fixed-shift-10 online LSE + label-matched pos-sum; LDS merge; atomicAdd/row.
__global__ __launch_bounds__(256) void lse_kernel(
    const unsigned short* __restrict__ nhat, const int* __restrict__ labels,
    const int* __restrict__ cnt, int N, int ntiles,
    float* __restrict__ loss_acc) {
  __shared__ float As[32][64];
  __shared__ float Bs[32][64];
  __shared__ float redS[64][17];
  __shared__ float redP[64][17];
  __shared__ int labS[640];
  const int tid = threadIdx.x;
  const int b = blockIdx.x / ntiles;
  const int tn = blockIdx.x - b * ntiles;
  const int n0 = tn * 64;
  const int tx4 = (tid & 15) * 4;
  const int ty4 = (tid >> 4) * 4;
  for (int i = tid; i < N; i += 256) labS[i] = labels[i];
  __syncthreads();
  int labn[4], nrow[4];
  #pragma unroll
  for (int i = 0; i < 4; ++i) {
    nrow[i] = n0 + ty4 + i;
    labn[i] = labS[nrow[i]];
  }
  float se[4] = {0.f, 0.f, 0.f, 0.f};
  float pos[4] = {0.f, 0.f, 0.f, 0.f};
  const size_t brow = (size_t)b * N;
  const int n_l = tid & 63;
  const int kb = (tid >> 6) << 3;  // 0,8,16,24
  const unsigned short* Arow = nhat + (brow + n0 + n_l) * DDIM + kb;
  for (int mt = 0; mt < ntiles; ++mt) {
    const int m0 = mt * 64;
    const unsigned short* Brow = nhat + (brow + m0 + n_l) * DDIM + kb;
    float acc[4][4];
    #pragma unroll
    for (int i = 0; i < 4; ++i)
      #pragma unroll
      for (int j = 0; j < 4; ++j) acc[i][j] = 0.f;
    for (int kc = 0; kc < 16; ++kc) {
      const uint4 va = *(const uint4*)(Arow + kc * 32);
      const uint4 vb = *(const uint4*)(Brow + kc * 32);
      store8(As, kb, n_l, va);
      store8(Bs, kb, n_l, vb);
      __syncthreads();
      #pragma unroll
      for (int k = 0; k < 32; ++k) {
        const float4 a = *(const float4*)&As[k][ty4];
        const float4 v = *(const float4*)&Bs[k][tx4];
        acc[0][0] = fmaf(a.x, v.x, acc[0][0]);
        acc[0][1] = fmaf(a.x, v.y, acc[0][1]);
        acc[0][2] = fmaf(a.x, v.z, acc[0][2]);
        acc[0][3] = fmaf(a.x, v.w, acc[0][3]);
        acc[1][0] = fmaf(a.y, v.x, acc[1][0]);
        acc[1][1] = fmaf(a.y, v.y, acc[1][1]);
        acc[1][2] = fmaf(a.y, v.z, acc[1][2]);
        acc[1][3] = fmaf(a.y, v.w, acc[1][3]);
        acc[2][0] = fmaf(a.z, v.x, acc[2][0]);
        acc[2][1] = fmaf(a.z, v.y, acc[2][1]);
        acc[2][2] = fmaf(a.z, v.z, acc[2][2]);
        acc[2][3] = fmaf(a.z, v.w, acc[2][3]);
        acc[3][0] = fmaf(a.w, v.x, acc[3][0]);
        acc[3][1] = fmaf(a.w, v.y, acc[3][1]);
        acc[3][2] = fmaf(a.w, v.z, acc[3][2]);
        acc[3][3] = fmaf(a.w, v.w, acc[3][3]);
      }
      __syncthreads();
    }
    #pragma unroll
    for (int i = 0; i < 4; ++i) {
      #pragma unroll
      for (int j = 0; j < 4; ++j) {
        const float sim = acc[i][j] * 10.0f;  // 1/TAU
        const int m = m0 + tx4 + j;
        se[i] += __expf(sim - 10.0f);         // fixed shift: row max = diag = 10
        if (labn[i] >= 0 && labS[m] == labn[i] && m != nrow[i]) pos[i] += sim;
      }
    }
  }
  #pragma unroll
  for (int i = 0; i < 4; ++i) {
    redS[ty4 + i][tid & 15] = se[i];
    redP[ty4 + i][tid & 15] = pos[i];
  }
  __syncthreads();
  if (tid < 64) {
    float s = 0.f, p = 0.f;
    #pragma unroll
    for (int t = 0; t < 16; ++t) {
      s += redS[tid][t];
      p += redP[tid][t];
    }
    const int c = cnt[n0 + tid];
    if (c > 0) atomicAdd(loss_acc, (10.0f + logf(s)) - p / (float)c);
  }
}

__global__ void final_kernel(const float* __restrict__ acc,
                             const int* __restrict__ valid,
                             float* __restrict__ out) {
  float l = 0.f;
  if (valid[0] > 0) l += acc[0] / (float)(BATCH * valid[0]);
  if (valid[1] > 0) l += acc[1] / (float)(BATCH * valid[1]);
  out[0] = l;
}

extern "C" void kernel_launch(void* const* d_in, const int* in_sizes, int n_in,
                              void* d_out, int out_size, void* d_ws,
                              size_t ws_size, hipStream_t stream) {
  const float* x0 = (const float*)d_in[0];
  const float* x1 = (const float*)d_in[1];
  const float* w0 = (const float*)d_in[2];
  const float* w1 = (const float*)d_in[3];
  const float* ehy0 = (const float*)d_in[4];
  const float* ehy1 = (const float*)d_in[5];
  const float* enod0 = (const float*)d_in[6];
  const float* enod1 = (const float*)d_in[7];

  float* out = (float*)d_out;
  float* adj0 = out;                       // 640*128
  float* adj1 = out + 640 * 128;           // 384*64
  float* lossp = out + 640 * 128 + 384 * 64;

  unsigned short* nhat0 = (unsigned short*)d_ws;
  unsigned short* nhat1 = nhat0 + (size_t)BATCH * 640 * DDIM;
  int* ip = (int*)(nhat1 + (size_t)BATCH * 384 * DDIM);
  int* labels0 = ip;
  int* labels1 = labels0 + 640;
  int* cnt0 = labels1 + 384;
  int* cnt1 = cnt0 + 640;
  int* valid = cnt1 + 384;
  float* acc = (float*)(valid + 2);

  init_kernel<<<1, 1, 0, stream>>>(acc);
  adj_kernel<<<640, 128, 0, stream>>>(enod0, ehy0, 640, 128, adj0, labels0);
  adj_kernel<<<384, 128, 0, stream>>>(enod1, ehy1, 384, 64, adj1, labels1);
  cnt_kernel<<<1, 256, 0, stream>>>(labels0, 640, cnt0, valid + 0);
  cnt_kernel<<<1, 256, 0, stream>>>(labels1, 384, cnt1, valid + 1);
  normalize_kernel<<<BATCH * 640, 128, 0, stream>>>(x0, w0, 512, 640, nhat0);
  normalize_kernel<<<BATCH * 384, 128, 0, stream>>>(x1, w1, 256, 384, nhat1);
  lse_kernel<<<BATCH * 10, 256, 0, stream>>>(nhat0, labels0, cnt0, 640, 10, acc + 0);
  lse_kernel<<<BATCH * 6, 256, 0, stream>>>(nhat1, labels1, cnt1, 384, 6, acc + 1);
  final_kernel<<<1, 1, 0, stream>>>(acc, valid, lossp);
}

// Round 3
// 671.134 us; speedup vs baseline: 1.4285x; 1.4285x over previous
//
#include <hip/hip_runtime.h>

// incidence_matrix_learn on MI355X — round 2 resubmit (round-2 bench died on
// container acquisition, not kernel): MFMA bf16 sim-GEMM.
// Algebraic simplifications (validated round 1, absmax 0.0):
//  - top-k mask is a no-op: adj_bin = (softmax(relu(3*a)) > 0.5), at most one per row
//  - P[n,m] = (label[n] == label[m] != -1) && n != m
//  - logsumexp row max is the diagonal sim = 1/TAU = 10 -> fixed-shift LSE
// Round-2 change: sim = nhat @ nhat^T via v_mfma_f32_16x16x32_bf16, fragments
// loaded DIRECTLY from global (A and B share the row-major B^T-GEMM pattern:
// row = base + (lane&15), k = ks*32 + (lane>>4)*8). No LDS in the K-loop.

#define DDIM 512
#define BATCH 64

typedef __attribute__((ext_vector_type(8))) short short8;
typedef __attribute__((ext_vector_type(4))) float f32x4;

__device__ __forceinline__ unsigned short f2bf(float f) {
  unsigned int u = __float_as_uint(f);
  u += 0x7fffu + ((u >> 16) & 1u);   // RNE
  return (unsigned short)(u >> 16);
}

__global__ void init_kernel(float* __restrict__ acc) {
  acc[0] = 0.f;
  acc[1] = 0.f;
}

// One block per node row n: a[h] = enod[n].ehy[h]; relu*3; softmax; >0.5 bin + label.
__global__ __launch_bounds__(128) void adj_kernel(
    const float* __restrict__ enod, const float* __restrict__ ehy,
    int N, int H, float* __restrict__ out_adj, int* __restrict__ labels) {
  const int n = blockIdx.x;
  const int t = threadIdx.x;
  __shared__ float erow[DDIM];
  __shared__ float red[128];
  __shared__ int lab;
  ((float4*)erow)[t] = ((const float4*)(enod + (size_t)n * DDIM))[t];
  if (t == 0) lab = -1;
  __syncthreads();
  float v = 0.f;
  if (t < H) {
    const float4* hr = (const float4*)(ehy + (size_t)t * DDIM);
    float a = 0.f;
    #pragma unroll 8
    for (int d = 0; d < DDIM / 4; ++d) {
      float4 h = hr[d];
      float4 e = ((const float4*)erow)[d];
      a = fmaf(h.x, e.x, a); a = fmaf(h.y, e.y, a);
      a = fmaf(h.z, e.z, a); a = fmaf(h.w, e.w, a);
    }
    v = fmaxf(0.f, 3.0f * a);
  }
  red[t] = v;
  __syncthreads();
  for (int s = 64; s > 0; s >>= 1) {
    if (t < s) red[t] = fmaxf(red[t], red[t + s]);
    __syncthreads();
  }
  const float mx = red[0];
  __syncthreads();
  const float e = (t < H) ? __expf(v - mx) : 0.f;
  red[t] = e;
  __syncthreads();
  for (int s = 64; s > 0; s >>= 1) {
    if (t < s) red[t] += red[t + s];
    __syncthreads();
  }
  const float sum = red[0];
  if (t < H) {
    const float adj = e / sum;
    const float bin = (adj > 0.5f) ? 1.0f : 0.0f;
    out_adj[(size_t)n * H + t] = bin;
    if (bin > 0.f) lab = t;
  }
  __syncthreads();
  if (t == 0) labels[n] = lab;
}

// Single block: cnt[n] = #{m != n : label[m] == label[n] != -1}; valid count.
__global__ __launch_bounds__(256) void cnt_kernel(
    const int* __restrict__ labels, int N, int* __restrict__ cnt,
    int* __restrict__ validcnt) {
  __shared__ int lab[640];
  __shared__ int vc;
  const int t = threadIdx.x;
  if (t == 0) vc = 0;
  for (int i = t; i < N; i += 256) lab[i] = labels[i];
  __syncthreads();
  for (int i = t; i < N; i += 256) {
    int c = 0;
    const int ln = lab[i];
    if (ln >= 0) {
      for (int m = 0; m < N; ++m) c += (m != i && lab[m] == ln) ? 1 : 0;
    }
    cnt[i] = c;
    if (c > 0) atomicAdd(&vc, 1);
  }
  __syncthreads();
  if (t == 0) *validcnt = vc;
}

// One block per (b, n): L2-normalize the node vector, store bf16 into nhat.
__global__ __launch_bounds__(128) void normalize_kernel(
    const float* __restrict__ x, const float* __restrict__ w,
    int L, int N, unsigned short* __restrict__ nhat) {
  const int bid = blockIdx.x;
  const int b = bid / N;
  const int n = bid - b * N;
  const int t = threadIdx.x;
  const float* src = (n < L) ? (x + ((size_t)b * L + n) * DDIM)
                             : (w + (size_t)(n - L) * DDIM);
  const float4 v = ((const float4*)src)[t];
  float ss = v.x * v.x + v.y * v.y + v.z * v.z + v.w * v.w;
  #pragma unroll
  for (int off = 32; off > 0; off >>= 1) ss += __shfl_down(ss, off);
  __shared__ float s2[2];
  if ((t & 63) == 0) s2[t >> 6] = ss;
  __syncthreads();
  const float rinv = 1.0f / fmaxf(sqrtf(s2[0] + s2[1]), 1e-12f);
  ushort4 o;
  o.x = f2bf(v.x * rinv);
  o.y = f2bf(v.y * rinv);
  o.z = f2bf(v.z * rinv);
  o.w = f2bf(v.w * rinv);
  ((ushort4*)(nhat + ((size_t)b * N + n) * DDIM))[t] = o;
}

// MFMA lse kernel: one block (4 waves) per (b, 64-row n-tile). Wave w owns
// rows rw0 = n0 + 16w .. +15. A frags preloaded (16 ksteps); per m-tile,
// 4 independent 16x16 output tiles (j) accumulate over 16 ksteps from
// global-loaded B frags. Epilogue: fixed-shift exp + label pos-sum in regs,
// shfl reduce over col lanes, one atomicAdd per valid row.
__global__ __launch_bounds__(256, 4) void lse_kernel(
    const unsigned short* __restrict__ nhat, const int* __restrict__ labels,
    const int* __restrict__ cnt, int N, int ntiles,
    float* __restrict__ loss_acc) {
  __shared__ int labS[640];
  __shared__ float redS[64];
  __shared__ float redP[64];
  const int tid = threadIdx.x;
  const int b = blockIdx.x / ntiles;
  const int tn = blockIdx.x - b * ntiles;
  const int n0 = tn * 64;
  const int wave = tid >> 6;
  const int lane = tid & 63;
  const int lrow = lane & 15;   // A-row / B-col within 16 / C-col
  const int lq = lane >> 4;     // k-chunk selector; C row group
  for (int i = tid; i < N; i += 256) labS[i] = labels[i];

  const size_t base = (size_t)b * N * DDIM;
  const int rw0 = n0 + wave * 16;
  const unsigned short* Aptr = nhat + base + (size_t)(rw0 + lrow) * DDIM + lq * 8;
  short8 a[16];
  #pragma unroll
  for (int ks = 0; ks < 16; ++ks) a[ks] = *(const short8*)(Aptr + ks * 32);
  __syncthreads();   // labS ready

  const int grow = rw0 + lq * 4;   // global row of acc[.][0]
  int labn[4];
  #pragma unroll
  for (int r = 0; r < 4; ++r) labn[r] = labS[grow + r];

  float se[4] = {0.f, 0.f, 0.f, 0.f};
  float pos[4] = {0.f, 0.f, 0.f, 0.f};

  for (int mt = 0; mt < ntiles; ++mt) {
    const int m0 = mt * 64;
    const unsigned short* Bptr =
        nhat + base + (size_t)(m0 + lrow) * DDIM + lq * 8;
    f32x4 acc[4];
    #pragma unroll
    for (int j = 0; j < 4; ++j) acc[j] = (f32x4){0.f, 0.f, 0.f, 0.f};
    #pragma unroll
    for (int ks = 0; ks < 16; ++ks) {
      short8 b0 = *(const short8*)(Bptr + 0 * 16 * DDIM + ks * 32);
      short8 b1 = *(const short8*)(Bptr + 1 * 16 * DDIM + ks * 32);
      short8 b2 = *(const short8*)(Bptr + 2 * 16 * DDIM + ks * 32);
      short8 b3 = *(const short8*)(Bptr + 3 * 16 * DDIM + ks * 32);
      acc[0] = __builtin_amdgcn_mfma_f32_16x16x32_bf16(a[ks], b0, acc[0], 0, 0, 0);
      acc[1] = __builtin_amdgcn_mfma_f32_16x16x32_bf16(a[ks], b1, acc[1], 0, 0, 0);
      acc[2] = __builtin_amdgcn_mfma_f32_16x16x32_bf16(a[ks], b2, acc[2], 0, 0, 0);
      acc[3] = __builtin_amdgcn_mfma_f32_16x16x32_bf16(a[ks], b3, acc[3], 0, 0, 0);
    }
    #pragma unroll
    for (int j = 0; j < 4; ++j) {
      const int m = m0 + j * 16 + lrow;   // C col = lane&15
      const int labm = labS[m];
      #pragma unroll
      for (int r = 0; r < 4; ++r) {       // C row = grow + r
        const float sim = acc[j][r] * 10.0f;          // 1/TAU
        se[r] += __expf(sim - 10.0f);                 // fixed shift (diag max)
        if (labn[r] >= 0 && labm == labn[r] && m != grow + r) pos[r] += sim;
      }
    }
  }
  // reduce across the 16 col-lanes of each row group (xor stays within group)
  #pragma unroll
  for (int off = 1; off <= 8; off <<= 1) {
    #pragma unroll
    for (int r = 0; r < 4; ++r) {
      se[r] += __shfl_xor(se[r], off);
      pos[r] += __shfl_xor(pos[r], off);
    }
  }
  if (lrow == 0) {
    #pragma unroll
    for (int r = 0; r < 4; ++r) {
      redS[wave * 16 + lq * 4 + r] = se[r];
      redP[wave * 16 + lq * 4 + r] = pos[r];
    }
  }
  __syncthreads();
  if (tid < 64) {
    const int c = cnt[n0 + tid];
    if (c > 0)
      atomicAdd(loss_acc, (10.0f + logf(redS[tid])) - redP[tid] / (float)c);
  }
}

__global__ void final_kernel(const float* __restrict__ acc,
                             const int* __restrict__ valid,
                             float* __restrict__ out) {
  float l = 0.f;
  if (valid[0] > 0) l += acc[0] / (float)(BATCH * valid[0]);
  if (valid[1] > 0) l += acc[1] / (float)(BATCH * valid[1]);
  out[0] = l;
}

extern "C" void kernel_launch(void* const* d_in, const int* in_sizes, int n_in,
                              void* d_out, int out_size, void* d_ws,
                              size_t ws_size, hipStream_t stream) {
  const float* x0 = (const float*)d_in[0];
  const float* x1 = (const float*)d_in[1];
  const float* w0 = (const float*)d_in[2];
  const float* w1 = (const float*)d_in[3];
  const float* ehy0 = (const float*)d_in[4];
  const float* ehy1 = (const float*)d_in[5];
  const float* enod0 = (const float*)d_in[6];
  const float* enod1 = (const float*)d_in[7];

  float* out = (float*)d_out;
  float* adj0 = out;                       // 640*128
  float* adj1 = out + 640 * 128;           // 384*64
  float* lossp = out + 640 * 128 + 384 * 64;

  unsigned short* nhat0 = (unsigned short*)d_ws;
  unsigned short* nhat1 = nhat0 + (size_t)BATCH * 640 * DDIM;
  int* ip = (int*)(nhat1 + (size_t)BATCH * 384 * DDIM);
  int* labels0 = ip;
  int* labels1 = labels0 + 640;
  int* cnt0 = labels1 + 384;
  int* cnt1 = cnt0 + 640;
  int* valid = cnt1 + 384;
  float* acc = (float*)(valid + 2);

  init_kernel<<<1, 1, 0, stream>>>(acc);
  adj_kernel<<<640, 128, 0, stream>>>(enod0, ehy0, 640, 128, adj0, labels0);
  adj_kernel<<<384, 128, 0, stream>>>(enod1, ehy1, 384, 64, adj1, labels1);
  cnt_kernel<<<1, 256, 0, stream>>>(labels0, 640, cnt0, valid + 0);
  cnt_kernel<<<1, 256, 0, stream>>>(labels1, 384, cnt1, valid + 1);
  normalize_kernel<<<BATCH * 640, 128, 0, stream>>>(x0, w0, 512, 640, nhat0);
  normalize_kernel<<<BATCH * 384, 128, 0, stream>>>(x1, w1, 256, 384, nhat1);
  lse_kernel<<<BATCH * 10, 256, 0, stream>>>(nhat0, labels0, cnt0, 640, 10, acc + 0);
  lse_kernel<<<BATCH * 6, 256, 0, stream>>>(nhat1, labels1, cnt1, 384, 6, acc + 1);
  final_kernel<<<1, 1, 0, stream>>>(acc, valid, lossp);
}

// Round 4
// 536.819 us; speedup vs baseline: 1.7859x; 1.2502x over previous
//
#include <hip/hip_runtime.h>

// incidence_matrix_learn on MI355X — round 4: LDS-staged pipelined lse kernel.
// Round-3 post-mortem: lse was latency-serialized (MfmaUtil 4.7%, VALUBusy 4.2%,
// 1 global load per MFMA, no prefetch regs) + 4x intra-block B redundancy.
// Round-4: B tiles staged via global_load_lds (16B) into double-buffered LDS
// chunks (64 m-rows x 128 k = 16 KB) in FRAG-ORDER layout: frag (j,ks) lives at
// chunk_base + (j*4+ks)*1024 + lane*16 — staging is 1 wave-issue per frag
// (wave-uniform LDS base + lane*16, matching the HW scatter rule) and the
// ds_read_b128 readback is lane-sequential (conflict-free). A frags stay in
// registers (64 VGPRs, reused across all m-tiles).
// Validated algebra (rounds 1-3, absmax 0.0): top-k no-op; P via labels;
// fixed-shift-10 LSE.

#define DDIM 512
#define BATCH 64

typedef __attribute__((ext_vector_type(8))) short short8;
typedef __attribute__((ext_vector_type(4))) float f32x4;

__device__ __forceinline__ unsigned short f2bf(float f) {
  unsigned int u = __float_as_uint(f);
  u += 0x7fffu + ((u >> 16) & 1u);   // RNE
  return (unsigned short)(u >> 16);
}

__device__ __forceinline__ void async16(const void* g, void* l) {
  __builtin_amdgcn_global_load_lds(
      (const __attribute__((address_space(1))) unsigned int*)g,
      (__attribute__((address_space(3))) unsigned int*)l, 16, 0, 0);
}

__global__ void init_kernel(float* __restrict__ acc) {
  acc[0] = 0.f;
  acc[1] = 0.f;
}

// One block per node row n: a[h] = enod[n].ehy[h]; relu*3; softmax; >0.5 bin + label.
__global__ __launch_bounds__(128) void adj_kernel(
    const float* __restrict__ enod, const float* __restrict__ ehy,
    int N, int H, float* __restrict__ out_adj, int* __restrict__ labels) {
  const int n = blockIdx.x;
  const int t = threadIdx.x;
  __shared__ float erow[DDIM];
  __shared__ float red[128];
  __shared__ int lab;
  ((float4*)erow)[t] = ((const float4*)(enod + (size_t)n * DDIM))[t];
  if (t == 0) lab = -1;
  __syncthreads();
  float v = 0.f;
  if (t < H) {
    const float4* hr = (const float4*)(ehy + (size_t)t * DDIM);
    float a = 0.f;
    #pragma unroll 8
    for (int d = 0; d < DDIM / 4; ++d) {
      float4 h = hr[d];
      float4 e = ((const float4*)erow)[d];
      a = fmaf(h.x, e.x, a); a = fmaf(h.y, e.y, a);
      a = fmaf(h.z, e.z, a); a = fmaf(h.w, e.w, a);
    }
    v = fmaxf(0.f, 3.0f * a);
  }
  red[t] = v;
  __syncthreads();
  for (int s = 64; s > 0; s >>= 1) {
    if (t < s) red[t] = fmaxf(red[t], red[t + s]);
    __syncthreads();
  }
  const float mx = red[0];
  __syncthreads();
  const float e = (t < H) ? __expf(v - mx) : 0.f;
  red[t] = e;
  __syncthreads();
  for (int s = 64; s > 0; s >>= 1) {
    if (t < s) red[t] += red[t + s];
    __syncthreads();
  }
  const float sum = red[0];
  if (t < H) {
    const float adj = e / sum;
    const float bin = (adj > 0.5f) ? 1.0f : 0.0f;
    out_adj[(size_t)n * H + t] = bin;
    if (bin > 0.f) lab = t;
  }
  __syncthreads();
  if (t == 0) labels[n] = lab;
}

// Single block: cnt[n] = #{m != n : label[m] == label[n] != -1}; valid count.
__global__ __launch_bounds__(256) void cnt_kernel(
    const int* __restrict__ labels, int N, int* __restrict__ cnt,
    int* __restrict__ validcnt) {
  __shared__ int lab[640];
  __shared__ int vc;
  const int t = threadIdx.x;
  if (t == 0) vc = 0;
  for (int i = t; i < N; i += 256) lab[i] = labels[i];
  __syncthreads();
  for (int i = t; i < N; i += 256) {
    int c = 0;
    const int ln = lab[i];
    if (ln >= 0) {
      for (int m = 0; m < N; ++m) c += (m != i && lab[m] == ln) ? 1 : 0;
    }
    cnt[i] = c;
    if (c > 0) atomicAdd(&vc, 1);
  }
  __syncthreads();
  if (t == 0) *validcnt = vc;
}

// One block per (b, n): L2-normalize the node vector, store bf16 into nhat.
__global__ __launch_bounds__(128) void normalize_kernel(
    const float* __restrict__ x, const float* __restrict__ w,
    int L, int N, unsigned short* __restrict__ nhat) {
  const int bid = blockIdx.x;
  const int b = bid / N;
  const int n = bid - b * N;
  const int t = threadIdx.x;
  const float* src = (n < L) ? (x + ((size_t)b * L + n) * DDIM)
                             : (w + (size_t)(n - L) * DDIM);
  const float4 v = ((const float4*)src)[t];
  float ss = v.x * v.x + v.y * v.y + v.z * v.z + v.w * v.w;
  #pragma unroll
  for (int off = 32; off > 0; off >>= 1) ss += __shfl_down(ss, off);
  __shared__ float s2[2];
  if ((t & 63) == 0) s2[t >> 6] = ss;
  __syncthreads();
  const float rinv = 1.0f / fmaxf(sqrtf(s2[0] + s2[1]), 1e-12f);
  ushort4 o;
  o.x = f2bf(v.x * rinv);
  o.y = f2bf(v.y * rinv);
  o.z = f2bf(v.z * rinv);
  o.w = f2bf(v.w * rinv);
  ((ushort4*)(nhat + ((size_t)b * N + n) * DDIM))[t] = o;
}

// Pipelined MFMA lse kernel. Block = 4 waves, 64-row n-tile; wave owns 16 rows
// (A frags: 16 x short8 = 64 VGPRs, all of K=512). m-loop runs over ntiles of
// 64 m-rows, split into 4 k-chunks of 128; chunk = 16 frags staged to LDS in
// frag order, double-buffered, prefetched one chunk ahead.
__global__ __launch_bounds__(256, 3) void lse_kernel(
    const unsigned short* __restrict__ nhat, const int* __restrict__ labels,
    const int* __restrict__ cnt, int N, int ntiles,
    float* __restrict__ loss_acc) {
  __shared__ short8 Bbuf[2][1024];   // 2 x 16 KB, frag-order
  __shared__ int labS[640];
  __shared__ float redS[64];
  __shared__ float redP[64];
  const int tid = threadIdx.x;
  const int b = blockIdx.x / ntiles;
  const int tn = blockIdx.x - b * ntiles;
  const int n0 = tn * 64;
  const int wave = tid >> 6;
  const int lane = tid & 63;
  const int lrow = lane & 15;   // A-row within 16 / B-col / C-col
  const int lq = lane >> 4;     // k-chunk selector / C row group
  for (int i = tid; i < N; i += 256) labS[i] = labels[i];

  const size_t base = (size_t)b * N * DDIM;
  const int rw0 = n0 + wave * 16;
  const unsigned short* Aptr = nhat + base + (size_t)(rw0 + lrow) * DDIM + lq * 8;
  short8 a[16];
  #pragma unroll
  for (int ks = 0; ks < 16; ++ks) a[ks] = *(const short8*)(Aptr + ks * 32);

  // stage chunk 0 (mt=0, kc=0): this wave's 4 frags f = wave*4 .. +3
  const int f0 = wave * 4;
  {
    #pragma unroll
    for (int fi = 0; fi < 4; ++fi) {
      const int f = f0 + fi;
      const int j = f >> 2, ks = f & 3;
      const unsigned short* g = nhat + base +
          (size_t)(j * 16 + lrow) * DDIM + ks * 32 + lq * 8;
      async16(g, &Bbuf[0][f * 64]);
    }
  }
  __syncthreads();   // drains staging (vmcnt) + labS + A loads

  const int grow = rw0 + lq * 4;   // global row of acc[.] element r=0
  int labn[4];
  #pragma unroll
  for (int r = 0; r < 4; ++r) labn[r] = labS[grow + r];

  float se[4] = {0.f, 0.f, 0.f, 0.f};
  float pos[4] = {0.f, 0.f, 0.f, 0.f};
  f32x4 acc[4];
  #pragma unroll
  for (int j = 0; j < 4; ++j) acc[j] = (f32x4){0.f, 0.f, 0.f, 0.f};

  const int nchunks = ntiles * 4;
  for (int c = 0; c < nchunks; ++c) {
    // prefetch chunk c+1 into the other buffer (fire-and-forget)
    if (c + 1 < nchunks) {
      const int c2 = c + 1;
      const int mt2 = c2 >> 2, kc2 = c2 & 3;
      short8* dst = &Bbuf[c2 & 1][0];
      #pragma unroll
      for (int fi = 0; fi < 4; ++fi) {
        const int f = f0 + fi;
        const int j = f >> 2, ks = f & 3;
        const unsigned short* g = nhat + base +
            (size_t)(mt2 * 64 + j * 16 + lrow) * DDIM +
            kc2 * 128 + ks * 32 + lq * 8;
        async16(g, dst + f * 64);
      }
    }
    // compute chunk c from Bbuf[c&1]
    {
      const short8* bb = &Bbuf[c & 1][0];
      #pragma unroll
      for (int ks = 0; ks < 4; ++ks) {
        const short8 b0 = bb[(0 + ks) * 64 + lane];
        const short8 b1 = bb[(4 + ks) * 64 + lane];
        const short8 b2 = bb[(8 + ks) * 64 + lane];
        const short8 b3 = bb[(12 + ks) * 64 + lane];
        const short8 av = a[(c & 3) * 4 + ks];
        acc[0] = __builtin_amdgcn_mfma_f32_16x16x32_bf16(av, b0, acc[0], 0, 0, 0);
        acc[1] = __builtin_amdgcn_mfma_f32_16x16x32_bf16(av, b1, acc[1], 0, 0, 0);
        acc[2] = __builtin_amdgcn_mfma_f32_16x16x32_bf16(av, b2, acc[2], 0, 0, 0);
        acc[3] = __builtin_amdgcn_mfma_f32_16x16x32_bf16(av, b3, acc[3], 0, 0, 0);
      }
    }
    // epilogue at the end of each m-tile (kc == 3)
    if ((c & 3) == 3) {
      const int m0 = (c >> 2) * 64;
      #pragma unroll
      for (int j = 0; j < 4; ++j) {
        const int m = m0 + j * 16 + lrow;
        const int labm = labS[m];
        #pragma unroll
        for (int r = 0; r < 4; ++r) {
          const float sim = acc[j][r] * 10.0f;       // 1/TAU
          se[r] += __expf(sim - 10.0f);              // fixed shift (diag max)
          if (labn[r] >= 0 && labm == labn[r] && m != grow + r) pos[r] += sim;
        }
        acc[j] = (f32x4){0.f, 0.f, 0.f, 0.f};
      }
    }
    __syncthreads();   // staging for c+1 drained; buffers safe to swap
  }

  // reduce across the 16 col-lanes of each row group
  #pragma unroll
  for (int off = 1; off <= 8; off <<= 1) {
    #pragma unroll
    for (int r = 0; r < 4; ++r) {
      se[r] += __shfl_xor(se[r], off);
      pos[r] += __shfl_xor(pos[r], off);
    }
  }
  if (lrow == 0) {
    #pragma unroll
    for (int r = 0; r < 4; ++r) {
      redS[wave * 16 + lq * 4 + r] = se[r];
      redP[wave * 16 + lq * 4 + r] = pos[r];
    }
  }
  __syncthreads();
  if (tid < 64) {
    const int c = cnt[n0 + tid];
    if (c > 0)
      atomicAdd(loss_acc, (10.0f + logf(redS[tid])) - redP[tid] / (float)c);
  }
}

__global__ void final_kernel(const float* __restrict__ acc,
                             const int* __restrict__ valid,
                             float* __restrict__ out) {
  float l = 0.f;
  if (valid[0] > 0) l += acc[0] / (float)(BATCH * valid[0]);
  if (valid[1] > 0) l += acc[1] / (float)(BATCH * valid[1]);
  out[0] = l;
}

extern "C" void kernel_launch(void* const* d_in, const int* in_sizes, int n_in,
                              void* d_out, int out_size, void* d_ws,
                              size_t ws_size, hipStream_t stream) {
  const float* x0 = (const float*)d_in[0];
  const float* x1 = (const float*)d_in[1];
  const float* w0 = (const float*)d_in[2];
  const float* w1 = (const float*)d_in[3];
  const float* ehy0 = (const float*)d_in[4];
  const float* ehy1 = (const float*)d_in[5];
  const float* enod0 = (const float*)d_in[6];
  const float* enod1 = (const float*)d_in[7];

  float* out = (float*)d_out;
  float* adj0 = out;                       // 640*128
  float* adj1 = out + 640 * 128;           // 384*64
  float* lossp = out + 640 * 128 + 384 * 64;

  unsigned short* nhat0 = (unsigned short*)d_ws;
  unsigned short* nhat1 = nhat0 + (size_t)BATCH * 640 * DDIM;
  int* ip = (int*)(nhat1 + (size_t)BATCH * 384 * DDIM);
  int* labels0 = ip;
  int* labels1 = labels0 + 640;
  int* cnt0 = labels1 + 384;
  int* cnt1 = cnt0 + 640;
  int* valid = cnt1 + 384;
  float* acc = (float*)(valid + 2);

  init_kernel<<<1, 1, 0, stream>>>(acc);
  adj_kernel<<<640, 128, 0, stream>>>(enod0, ehy0, 640, 128, adj0, labels0);
  adj_kernel<<<384, 128, 0, stream>>>(enod1, ehy1, 384, 64, adj1, labels1);
  cnt_kernel<<<1, 256, 0, stream>>>(labels0, 640, cnt0, valid + 0);
  cnt_kernel<<<1, 256, 0, stream>>>(labels1, 384, cnt1, valid + 1);
  normalize_kernel<<<BATCH * 640, 128, 0, stream>>>(x0, w0, 512, 640, nhat0);
  normalize_kernel<<<BATCH * 384, 128, 0, stream>>>(x1, w1, 256, 384, nhat1);
  lse_kernel<<<BATCH * 10, 256, 0, stream>>>(nhat0, labels0, cnt0, 640, 10, acc + 0);
  lse_kernel<<<BATCH * 6, 256, 0, stream>>>(nhat1, labels1, cnt1, 384, 6, acc + 1);
  final_kernel<<<1, 1, 0, stream>>>(acc, valid, lossp);
}

// Round 6
// 375.684 us; speedup vs baseline: 2.5519x; 1.4289x over previous
//
#include <hip/hip_runtime.h>

// incidence_matrix_learn on MI355X — round 5 resubmit (round-5 bench died on
// container acquisition, not kernel).
// Round-4 post-mortem: a[16] was dynamically indexed inside a runtime loop ->
// compiler demoted it to SCRATCH (VGPR_Count=52, WRITE_SIZE=40MB, FETCH 387MB,
// MfmaUtil 7%). Fixes: (a) mt-loop with fully-unrolled kc in [0,4) so a[] index
// and buffer parity are compile-time; (b) XCD swizzle b=blockIdx%64 (all tiles
// of a batch share an XCD's L2); (c) kernel fusion 10 launches -> 5.
// Validated algebra (rounds 1-4, absmax 0.0): top-k no-op; P via labels;
// fixed-shift-10 LSE; bf16 nhat.

#define DDIM 512
#define BATCH 64

typedef __attribute__((ext_vector_type(8))) short short8;
typedef __attribute__((ext_vector_type(4))) float f32x4;

__device__ __forceinline__ unsigned short f2bf(float f) {
  unsigned int u = __float_as_uint(f);
  u += 0x7fffu + ((u >> 16) & 1u);   // RNE
  return (unsigned short)(u >> 16);
}

__device__ __forceinline__ void async16(const void* g, void* l) {
  __builtin_amdgcn_global_load_lds(
      (const __attribute__((address_space(1))) unsigned int*)g,
      (__attribute__((address_space(3))) unsigned int*)l, 16, 0, 0);
}

// Merged adj (both scales) + acc zero-init. Blocks [0,640): scale0; [640,1024): scale1.
__global__ __launch_bounds__(128) void adj_kernel(
    const float* __restrict__ enod0, const float* __restrict__ ehy0,
    const float* __restrict__ enod1, const float* __restrict__ ehy1,
    float* __restrict__ adj0, float* __restrict__ adj1,
    int* __restrict__ labels0, int* __restrict__ labels1,
    float* __restrict__ acc) {
  const int t = threadIdx.x;
  if (blockIdx.x == 0 && t == 0) { acc[0] = 0.f; acc[1] = 0.f; }
  const bool s0 = blockIdx.x < 640;
  const int n = s0 ? blockIdx.x : blockIdx.x - 640;
  const int H = s0 ? 128 : 64;
  const float* enod = s0 ? enod0 : enod1;
  const float* ehy = s0 ? ehy0 : ehy1;
  float* out_adj = s0 ? adj0 : adj1;
  int* labels = s0 ? labels0 : labels1;

  __shared__ float erow[DDIM];
  __shared__ float red[128];
  __shared__ int lab;
  ((float4*)erow)[t] = ((const float4*)(enod + (size_t)n * DDIM))[t];
  if (t == 0) lab = -1;
  __syncthreads();
  float v = 0.f;
  if (t < H) {
    const float4* hr = (const float4*)(ehy + (size_t)t * DDIM);
    float a = 0.f;
    #pragma unroll 8
    for (int d = 0; d < DDIM / 4; ++d) {
      float4 h = hr[d];
      float4 e = ((const float4*)erow)[d];
      a = fmaf(h.x, e.x, a); a = fmaf(h.y, e.y, a);
      a = fmaf(h.z, e.z, a); a = fmaf(h.w, e.w, a);
    }
    v = fmaxf(0.f, 3.0f * a);
  }
  red[t] = v;
  __syncthreads();
  for (int s = 64; s > 0; s >>= 1) {
    if (t < s) red[t] = fmaxf(red[t], red[t + s]);
    __syncthreads();
  }
  const float mx = red[0];
  __syncthreads();
  const float e = (t < H) ? __expf(v - mx) : 0.f;
  red[t] = e;
  __syncthreads();
  for (int s = 64; s > 0; s >>= 1) {
    if (t < s) red[t] += red[t + s];
    __syncthreads();
  }
  const float sum = red[0];
  if (t < H) {
    const float adj = e / sum;
    const float bin = (adj > 0.5f) ? 1.0f : 0.0f;
    out_adj[(size_t)n * H + t] = bin;
    if (bin > 0.f) lab = t;
  }
  __syncthreads();
  if (t == 0) labels[n] = lab;
}

// 2 blocks: cnt[n] = #{m != n : label[m] == label[n] != -1}; valid count.
__global__ __launch_bounds__(256) void cnt_kernel(
    const int* __restrict__ labels0, int* __restrict__ cnt0,
    const int* __restrict__ labels1, int* __restrict__ cnt1,
    int* __restrict__ valid) {
  const bool s0 = blockIdx.x == 0;
  const int* labels = s0 ? labels0 : labels1;
  int* cnt = s0 ? cnt0 : cnt1;
  int* validcnt = s0 ? valid : valid + 1;
  const int N = s0 ? 640 : 384;
  __shared__ int lab[640];
  __shared__ int vc;
  const int t = threadIdx.x;
  if (t == 0) vc = 0;
  for (int i = t; i < N; i += 256) lab[i] = labels[i];
  __syncthreads();
  for (int i = t; i < N; i += 256) {
    int c = 0;
    const int ln = lab[i];
    if (ln >= 0) {
      for (int m = 0; m < N; ++m) c += (m != i && lab[m] == ln) ? 1 : 0;
    }
    cnt[i] = c;
    if (c > 0) atomicAdd(&vc, 1);
  }
  __syncthreads();
  if (t == 0) *validcnt = vc;
}

// Merged normalize: blocks [0, 64*640) scale0; rest scale1.
__global__ __launch_bounds__(128) void normalize_kernel(
    const float* __restrict__ x0, const float* __restrict__ w0,
    const float* __restrict__ x1, const float* __restrict__ w1,
    unsigned short* __restrict__ nhat0, unsigned short* __restrict__ nhat1) {
  int bid = blockIdx.x;
  const bool s0 = bid < BATCH * 640;
  if (!s0) bid -= BATCH * 640;
  const int N = s0 ? 640 : 384;
  const int L = s0 ? 512 : 256;
  const float* x = s0 ? x0 : x1;
  const float* w = s0 ? w0 : w1;
  unsigned short* nhat = s0 ? nhat0 : nhat1;
  const int b = bid / N;
  const int n = bid - b * N;
  const int t = threadIdx.x;
  const float* src = (n < L) ? (x + ((size_t)b * L + n) * DDIM)
                             : (w + (size_t)(n - L) * DDIM);
  const float4 v = ((const float4*)src)[t];
  float ss = v.x * v.x + v.y * v.y + v.z * v.z + v.w * v.w;
  #pragma unroll
  for (int off = 32; off > 0; off >>= 1) ss += __shfl_down(ss, off);
  __shared__ float s2[2];
  if ((t & 63) == 0) s2[t >> 6] = ss;
  __syncthreads();
  const float rinv = 1.0f / fmaxf(sqrtf(s2[0] + s2[1]), 1e-12f);
  ushort4 o;
  o.x = f2bf(v.x * rinv);
  o.y = f2bf(v.y * rinv);
  o.z = f2bf(v.z * rinv);
  o.w = f2bf(v.w * rinv);
  ((ushort4*)(nhat + ((size_t)b * N + n) * DDIM))[t] = o;
}

// Merged pipelined MFMA lse kernel. Blocks [0,640): scale0 (10 tiles/batch);
// [640,1024): scale1 (6 tiles/batch). XCD swizzle: b = i % 64 (64 % 8 == 0 so
// all tiles of a batch share one XCD's L2). Wave owns 16 rows, A frags in 64
// VGPRs; B staged to double-buffered frag-order LDS chunks (64 m x 128 k),
// prefetched one chunk ahead via global_load_lds(16B). kc fully unrolled so
// a[] indices + buffer parity are compile-time (round-4 scratch-spill fix).
__global__ __launch_bounds__(256, 3) void lse_kernel(
    const unsigned short* __restrict__ nhat0, const int* __restrict__ labels0,
    const int* __restrict__ cnt0, const unsigned short* __restrict__ nhat1,
    const int* __restrict__ labels1, const int* __restrict__ cnt1,
    float* __restrict__ loss_acc) {
  __shared__ short8 Bbuf[2][1024];   // 2 x 16 KB, frag-order
  __shared__ int labS[640];
  __shared__ float redS[64];
  __shared__ float redP[64];
  const int tid = threadIdx.x;
  const bool s0 = blockIdx.x < 640;
  const int i = s0 ? blockIdx.x : blockIdx.x - 640;
  const int N = s0 ? 640 : 384;
  const int ntiles = s0 ? 10 : 6;
  const unsigned short* nhat = s0 ? nhat0 : nhat1;
  const int* labels = s0 ? labels0 : labels1;
  const int* cnt = s0 ? cnt0 : cnt1;
  float* acc_out = s0 ? loss_acc : loss_acc + 1;
  const int b = i & 63;        // XCD swizzle: batch fixes XCD residue
  const int tn = i >> 6;
  const int n0 = tn * 64;
  const int wave = tid >> 6;
  const int lane = tid & 63;
  const int lrow = lane & 15;   // A-row within 16 / B-col / C-col
  const int lq = lane >> 4;     // k-chunk selector / C row group
  for (int t = tid; t < N; t += 256) labS[t] = labels[t];

  const size_t base = (size_t)b * N * DDIM;
  const int rw0 = n0 + wave * 16;
  const unsigned short* Aptr = nhat + base + (size_t)(rw0 + lrow) * DDIM + lq * 8;
  short8 a[16];
  #pragma unroll
  for (int ks = 0; ks < 16; ++ks) a[ks] = *(const short8*)(Aptr + ks * 32);

  // stage chunk 0 (mt=0, kc=0): this wave's 4 frags f = wave*4 .. +3
  const int f0 = wave * 4;
  #pragma unroll
  for (int fi = 0; fi < 4; ++fi) {
    const int f = f0 + fi;
    const int j = f >> 2, ks = f & 3;
    const unsigned short* g = nhat + base +
        (size_t)(j * 16 + lrow) * DDIM + ks * 32 + lq * 8;
    async16(g, &Bbuf[0][f * 64]);
  }
  __syncthreads();   // drains staging (vmcnt) + labS writes

  const int grow = rw0 + lq * 4;   // global row of acc[.] element r
  int labn[4];
  #pragma unroll
  for (int r = 0; r < 4; ++r) labn[r] = labS[grow + r];

  float se[4] = {0.f, 0.f, 0.f, 0.f};
  float pos[4] = {0.f, 0.f, 0.f, 0.f};
  const int nchunks = ntiles * 4;

  for (int mt = 0; mt < ntiles; ++mt) {
    f32x4 acc[4];
    #pragma unroll
    for (int j = 0; j < 4; ++j) acc[j] = (f32x4){0.f, 0.f, 0.f, 0.f};
    #pragma unroll
    for (int kc = 0; kc < 4; ++kc) {
      // prefetch chunk (mt*4 + kc + 1) into buffer parity (kc+1)&1
      const int nc = mt * 4 + kc + 1;
      if (nc < nchunks) {
        const int mt2 = nc >> 2, kc2 = nc & 3;
        short8* dst = &Bbuf[(kc + 1) & 1][0];
        #pragma unroll
        for (int fi = 0; fi < 4; ++fi) {
          const int f = f0 + fi;
          const int j = f >> 2, ks = f & 3;
          const unsigned short* g = nhat + base +
              (size_t)(mt2 * 64 + j * 16 + lrow) * DDIM +
              kc2 * 128 + ks * 32 + lq * 8;
          async16(g, dst + f * 64);
        }
      }
      // compute chunk kc from Bbuf[kc&1]; a[] index is compile-time
      const short8* bb = &Bbuf[kc & 1][0];
      #pragma unroll
      for (int ks = 0; ks < 4; ++ks) {
        const short8 b0 = bb[(0 + ks) * 64 + lane];
        const short8 b1 = bb[(4 + ks) * 64 + lane];
        const short8 b2 = bb[(8 + ks) * 64 + lane];
        const short8 b3 = bb[(12 + ks) * 64 + lane];
        const short8 av = a[kc * 4 + ks];
        acc[0] = __builtin_amdgcn_mfma_f32_16x16x32_bf16(av, b0, acc[0], 0, 0, 0);
        acc[1] = __builtin_amdgcn_mfma_f32_16x16x32_bf16(av, b1, acc[1], 0, 0, 0);
        acc[2] = __builtin_amdgcn_mfma_f32_16x16x32_bf16(av, b2, acc[2], 0, 0, 0);
        acc[3] = __builtin_amdgcn_mfma_f32_16x16x32_bf16(av, b3, acc[3], 0, 0, 0);
      }
      __syncthreads();   // staging for nc drained; buffer swap safe
    }
    // epilogue for this m-tile
    const int m0 = mt * 64;
    #pragma unroll
    for (int j = 0; j < 4; ++j) {
      const int m = m0 + j * 16 + lrow;
      const int labm = labS[m];
      #pragma unroll
      for (int r = 0; r < 4; ++r) {
        const float sim = acc[j][r] * 10.0f;       // 1/TAU
        se[r] += __expf(sim - 10.0f);              // fixed shift (diag max)
        if (labn[r] >= 0 && labm == labn[r] && m != grow + r) pos[r] += sim;
      }
    }
  }

  // reduce across the 16 col-lanes of each row group
  #pragma unroll
  for (int off = 1; off <= 8; off <<= 1) {
    #pragma unroll
    for (int r = 0; r < 4; ++r) {
      se[r] += __shfl_xor(se[r], off);
      pos[r] += __shfl_xor(pos[r], off);
    }
  }
  if (lrow == 0) {
    #pragma unroll
    for (int r = 0; r < 4; ++r) {
      redS[wave * 16 + lq * 4 + r] = se[r];
      redP[wave * 16 + lq * 4 + r] = pos[r];
    }
  }
  __syncthreads();
  if (tid < 64) {
    const int c = cnt[n0 + tid];
    if (c > 0)
      atomicAdd(acc_out, (10.0f + logf(redS[tid])) - redP[tid] / (float)c);
  }
}

__global__ void final_kernel(const float* __restrict__ acc,
                             const int* __restrict__ valid,
                             float* __restrict__ out) {
  float l = 0.f;
  if (valid[0] > 0) l += acc[0] / (float)(BATCH * valid[0]);
  if (valid[1] > 0) l += acc[1] / (float)(BATCH * valid[1]);
  out[0] = l;
}

extern "C" void kernel_launch(void* const* d_in, const int* in_sizes, int n_in,
                              void* d_out, int out_size, void* d_ws,
                              size_t ws_size, hipStream_t stream) {
  const float* x0 = (const float*)d_in[0];
  const float* x1 = (const float*)d_in[1];
  const float* w0 = (const float*)d_in[2];
  const float* w1 = (const float*)d_in[3];
  const float* ehy0 = (const float*)d_in[4];
  const float* ehy1 = (const float*)d_in[5];
  const float* enod0 = (const float*)d_in[6];
  const float* enod1 = (const float*)d_in[7];

  float* out = (float*)d_out;
  float* adj0 = out;                       // 640*128
  float* adj1 = out + 640 * 128;           // 384*64
  float* lossp = out + 640 * 128 + 384 * 64;

  unsigned short* nhat0 = (unsigned short*)d_ws;
  unsigned short* nhat1 = nhat0 + (size_t)BATCH * 640 * DDIM;
  int* ip = (int*)(nhat1 + (size_t)BATCH * 384 * DDIM);
  int* labels0 = ip;
  int* labels1 = labels0 + 640;
  int* cnt0 = labels1 + 384;
  int* cnt1 = cnt0 + 640;
  int* valid = cnt1 + 384;
  float* acc = (float*)(valid + 2);

  adj_kernel<<<1024, 128, 0, stream>>>(enod0, ehy0, enod1, ehy1, adj0, adj1,
                                       labels0, labels1, acc);
  cnt_kernel<<<2, 256, 0, stream>>>(labels0, cnt0, labels1, cnt1, valid);
  normalize_kernel<<<BATCH * (640 + 384), 128, 0, stream>>>(x0, w0, x1, w1,
                                                            nhat0, nhat1);
  lse_kernel<<<1024, 256, 0, stream>>>(nhat0, labels0, cnt0, nhat1, labels1,
                                       cnt1, acc);
  final_kernel<<<1, 1, 0, stream>>>(acc, valid, lossp);
}

// Round 7
// 264.103 us; speedup vs baseline: 3.6301x; 1.4225x over previous
//
#include <hip/hip_runtime.h>

// incidence_matrix_learn on MI355X — round 7.
// Round-6 post-mortem: cnt_kernel was the TOP dispatch (116 µs, VALUBusy 0.06%)
// — runtime-bound inner loop => one latency-serialized ds_read_b32 (~120 cyc)
// per iteration x 1920 iterations. Fix: cnt[i] = hist[lab[i]] - 1 via a
// 128-bin LDS label histogram (O(N) with LDS atomics). Everything else
// unchanged from round 5 (total 537 -> 376 µs, lse fixes validated).
// Validated algebra (rounds 1-6, absmax 0.0): top-k no-op; P via labels;
// fixed-shift-10 LSE; bf16 nhat; cnt == per-label population - 1.

#define DDIM 512
#define BATCH 64

typedef __attribute__((ext_vector_type(8))) short short8;
typedef __attribute__((ext_vector_type(4))) float f32x4;

__device__ __forceinline__ unsigned short f2bf(float f) {
  unsigned int u = __float_as_uint(f);
  u += 0x7fffu + ((u >> 16) & 1u);   // RNE
  return (unsigned short)(u >> 16);
}

__device__ __forceinline__ void async16(const void* g, void* l) {
  __builtin_amdgcn_global_load_lds(
      (const __attribute__((address_space(1))) unsigned int*)g,
      (__attribute__((address_space(3))) unsigned int*)l, 16, 0, 0);
}

// Merged adj (both scales) + acc zero-init. Blocks [0,640): scale0; [640,1024): scale1.
__global__ __launch_bounds__(128) void adj_kernel(
    const float* __restrict__ enod0, const float* __restrict__ ehy0,
    const float* __restrict__ enod1, const float* __restrict__ ehy1,
    float* __restrict__ adj0, float* __restrict__ adj1,
    int* __restrict__ labels0, int* __restrict__ labels1,
    float* __restrict__ acc) {
  const int t = threadIdx.x;
  if (blockIdx.x == 0 && t == 0) { acc[0] = 0.f; acc[1] = 0.f; }
  const bool s0 = blockIdx.x < 640;
  const int n = s0 ? blockIdx.x : blockIdx.x - 640;
  const int H = s0 ? 128 : 64;
  const float* enod = s0 ? enod0 : enod1;
  const float* ehy = s0 ? ehy0 : ehy1;
  float* out_adj = s0 ? adj0 : adj1;
  int* labels = s0 ? labels0 : labels1;

  __shared__ float erow[DDIM];
  __shared__ float red[128];
  __shared__ int lab;
  ((float4*)erow)[t] = ((const float4*)(enod + (size_t)n * DDIM))[t];
  if (t == 0) lab = -1;
  __syncthreads();
  float v = 0.f;
  if (t < H) {
    const float4* hr = (const float4*)(ehy + (size_t)t * DDIM);
    float a = 0.f;
    #pragma unroll 8
    for (int d = 0; d < DDIM / 4; ++d) {
      float4 h = hr[d];
      float4 e = ((const float4*)erow)[d];
      a = fmaf(h.x, e.x, a); a = fmaf(h.y, e.y, a);
      a = fmaf(h.z, e.z, a); a = fmaf(h.w, e.w, a);
    }
    v = fmaxf(0.f, 3.0f * a);
  }
  red[t] = v;
  __syncthreads();
  for (int s = 64; s > 0; s >>= 1) {
    if (t < s) red[t] = fmaxf(red[t], red[t + s]);
    __syncthreads();
  }
  const float mx = red[0];
  __syncthreads();
  const float e = (t < H) ? __expf(v - mx) : 0.f;
  red[t] = e;
  __syncthreads();
  for (int s = 64; s > 0; s >>= 1) {
    if (t < s) red[t] += red[t + s];
    __syncthreads();
  }
  const float sum = red[0];
  if (t < H) {
    const float adj = e / sum;
    const float bin = (adj > 0.5f) ? 1.0f : 0.0f;
    out_adj[(size_t)n * H + t] = bin;
    if (bin > 0.f) lab = t;
  }
  __syncthreads();
  if (t == 0) labels[n] = lab;
}

// 2 blocks. cnt[i] = hist[lab[i]] - 1 via 128-bin LDS label histogram.
__global__ __launch_bounds__(256) void cnt_kernel(
    const int* __restrict__ labels0, int* __restrict__ cnt0,
    const int* __restrict__ labels1, int* __restrict__ cnt1,
    int* __restrict__ valid) {
  const bool s0 = blockIdx.x == 0;
  const int* labels = s0 ? labels0 : labels1;
  int* cnt = s0 ? cnt0 : cnt1;
  int* validcnt = s0 ? valid : valid + 1;
  const int N = s0 ? 640 : 384;
  __shared__ int lab[640];
  __shared__ int hist[128];
  __shared__ int vc;
  const int t = threadIdx.x;
  if (t == 0) vc = 0;
  if (t < 128) hist[t] = 0;
  for (int i = t; i < N; i += 256) lab[i] = labels[i];
  __syncthreads();
  for (int i = t; i < N; i += 256)
    if (lab[i] >= 0) atomicAdd(&hist[lab[i]], 1);
  __syncthreads();
  int lv = 0;
  for (int i = t; i < N; i += 256) {
    const int c = (lab[i] >= 0) ? hist[lab[i]] - 1 : 0;
    cnt[i] = c;
    if (c > 0) ++lv;
  }
  if (lv > 0) atomicAdd(&vc, lv);
  __syncthreads();
  if (t == 0) *validcnt = vc;
}

// Merged normalize: blocks [0, 64*640) scale0; rest scale1.
__global__ __launch_bounds__(128) void normalize_kernel(
    const float* __restrict__ x0, const float* __restrict__ w0,
    const float* __restrict__ x1, const float* __restrict__ w1,
    unsigned short* __restrict__ nhat0, unsigned short* __restrict__ nhat1) {
  int bid = blockIdx.x;
  const bool s0 = bid < BATCH * 640;
  if (!s0) bid -= BATCH * 640;
  const int N = s0 ? 640 : 384;
  const int L = s0 ? 512 : 256;
  const float* x = s0 ? x0 : x1;
  const float* w = s0 ? w0 : w1;
  unsigned short* nhat = s0 ? nhat0 : nhat1;
  const int b = bid / N;
  const int n = bid - b * N;
  const int t = threadIdx.x;
  const float* src = (n < L) ? (x + ((size_t)b * L + n) * DDIM)
                             : (w + (size_t)(n - L) * DDIM);
  const float4 v = ((const float4*)src)[t];
  float ss = v.x * v.x + v.y * v.y + v.z * v.z + v.w * v.w;
  #pragma unroll
  for (int off = 32; off > 0; off >>= 1) ss += __shfl_down(ss, off);
  __shared__ float s2[2];
  if ((t & 63) == 0) s2[t >> 6] = ss;
  __syncthreads();
  const float rinv = 1.0f / fmaxf(sqrtf(s2[0] + s2[1]), 1e-12f);
  ushort4 o;
  o.x = f2bf(v.x * rinv);
  o.y = f2bf(v.y * rinv);
  o.z = f2bf(v.z * rinv);
  o.w = f2bf(v.w * rinv);
  ((ushort4*)(nhat + ((size_t)b * N + n) * DDIM))[t] = o;
}

// Merged pipelined MFMA lse kernel. Blocks [0,640): scale0 (10 tiles/batch);
// [640,1024): scale1 (6 tiles/batch). XCD swizzle: b = i % 64. Wave owns 16
// rows, A frags in 64 VGPRs; B staged to double-buffered frag-order LDS chunks
// (64 m x 128 k), prefetched one chunk ahead via global_load_lds(16B). kc
// fully unrolled so a[] indices + buffer parity are compile-time.
__global__ __launch_bounds__(256, 3) void lse_kernel(
    const unsigned short* __restrict__ nhat0, const int* __restrict__ labels0,
    const int* __restrict__ cnt0, const unsigned short* __restrict__ nhat1,
    const int* __restrict__ labels1, const int* __restrict__ cnt1,
    float* __restrict__ loss_acc) {
  __shared__ short8 Bbuf[2][1024];   // 2 x 16 KB, frag-order
  __shared__ int labS[640];
  __shared__ float redS[64];
  __shared__ float redP[64];
  const int tid = threadIdx.x;
  const bool s0 = blockIdx.x < 640;
  const int i = s0 ? blockIdx.x : blockIdx.x - 640;
  const int N = s0 ? 640 : 384;
  const int ntiles = s0 ? 10 : 6;
  const unsigned short* nhat = s0 ? nhat0 : nhat1;
  const int* labels = s0 ? labels0 : labels1;
  const int* cnt = s0 ? cnt0 : cnt1;
  float* acc_out = s0 ? loss_acc : loss_acc + 1;
  const int b = i & 63;        // XCD swizzle: batch fixes XCD residue
  const int tn = i >> 6;
  const int n0 = tn * 64;
  const int wave = tid >> 6;
  const int lane = tid & 63;
  const int lrow = lane & 15;   // A-row within 16 / B-col / C-col
  const int lq = lane >> 4;     // k-chunk selector / C row group
  for (int t = tid; t < N; t += 256) labS[t] = labels[t];

  const size_t base = (size_t)b * N * DDIM;
  const int rw0 = n0 + wave * 16;
  const unsigned short* Aptr = nhat + base + (size_t)(rw0 + lrow) * DDIM + lq * 8;
  short8 a[16];
  #pragma unroll
  for (int ks = 0; ks < 16; ++ks) a[ks] = *(const short8*)(Aptr + ks * 32);

  // stage chunk 0 (mt=0, kc=0): this wave's 4 frags f = wave*4 .. +3
  const int f0 = wave * 4;
  #pragma unroll
  for (int fi = 0; fi < 4; ++fi) {
    const int f = f0 + fi;
    const int j = f >> 2, ks = f & 3;
    const unsigned short* g = nhat + base +
        (size_t)(j * 16 + lrow) * DDIM + ks * 32 + lq * 8;
    async16(g, &Bbuf[0][f * 64]);
  }
  __syncthreads();   // drains staging (vmcnt) + labS writes

  const int grow = rw0 + lq * 4;   // global row of acc[.] element r
  int labn[4];
  #pragma unroll
  for (int r = 0; r < 4; ++r) labn[r] = labS[grow + r];

  float se[4] = {0.f, 0.f, 0.f, 0.f};
  float pos[4] = {0.f, 0.f, 0.f, 0.f};
  const int nchunks = ntiles * 4;

  for (int mt = 0; mt < ntiles; ++mt) {
    f32x4 acc[4];
    #pragma unroll
    for (int j = 0; j < 4; ++j) acc[j] = (f32x4){0.f, 0.f, 0.f, 0.f};
    #pragma unroll
    for (int kc = 0; kc < 4; ++kc) {
      // prefetch chunk (mt*4 + kc + 1) into buffer parity (kc+1)&1
      const int nc = mt * 4 + kc + 1;
      if (nc < nchunks) {
        const int mt2 = nc >> 2, kc2 = nc & 3;
        short8* dst = &Bbuf[(kc + 1) & 1][0];
        #pragma unroll
        for (int fi = 0; fi < 4; ++fi) {
          const int f = f0 + fi;
          const int j = f >> 2, ks = f & 3;
          const unsigned short* g = nhat + base +
              (size_t)(mt2 * 64 + j * 16 + lrow) * DDIM +
              kc2 * 128 + ks * 32 + lq * 8;
          async16(g, dst + f * 64);
        }
      }
      // compute chunk kc from Bbuf[kc&1]; a[] index is compile-time
      const short8* bb = &Bbuf[kc & 1][0];
      #pragma unroll
      for (int ks = 0; ks < 4; ++ks) {
        const short8 b0 = bb[(0 + ks) * 64 + lane];
        const short8 b1 = bb[(4 + ks) * 64 + lane];
        const short8 b2 = bb[(8 + ks) * 64 + lane];
        const short8 b3 = bb[(12 + ks) * 64 + lane];
        const short8 av = a[kc * 4 + ks];
        acc[0] = __builtin_amdgcn_mfma_f32_16x16x32_bf16(av, b0, acc[0], 0, 0, 0);
        acc[1] = __builtin_amdgcn_mfma_f32_16x16x32_bf16(av, b1, acc[1], 0, 0, 0);
        acc[2] = __builtin_amdgcn_mfma_f32_16x16x32_bf16(av, b2, acc[2], 0, 0, 0);
        acc[3] = __builtin_amdgcn_mfma_f32_16x16x32_bf16(av, b3, acc[3], 0, 0, 0);
      }
      __syncthreads();   // staging for nc drained; buffer swap safe
    }
    // epilogue for this m-tile
    const int m0 = mt * 64;
    #pragma unroll
    for (int j = 0; j < 4; ++j) {
      const int m = m0 + j * 16 + lrow;
      const int labm = labS[m];
      #pragma unroll
      for (int r = 0; r < 4; ++r) {
        const float sim = acc[j][r] * 10.0f;       // 1/TAU
        se[r] += __expf(sim - 10.0f);              // fixed shift (diag max)
        if (labn[r] >= 0 && labm == labn[r] && m != grow + r) pos[r] += sim;
      }
    }
  }

  // reduce across the 16 col-lanes of each row group
  #pragma unroll
  for (int off = 1; off <= 8; off <<= 1) {
    #pragma unroll
    for (int r = 0; r < 4; ++r) {
      se[r] += __shfl_xor(se[r], off);
      pos[r] += __shfl_xor(pos[r], off);
    }
  }
  if (lrow == 0) {
    #pragma unroll
    for (int r = 0; r < 4; ++r) {
      redS[wave * 16 + lq * 4 + r] = se[r];
      redP[wave * 16 + lq * 4 + r] = pos[r];
    }
  }
  __syncthreads();
  if (tid < 64) {
    const int c = cnt[n0 + tid];
    if (c > 0)
      atomicAdd(acc_out, (10.0f + logf(redS[tid])) - redP[tid] / (float)c);
  }
}

__global__ void final_kernel(const float* __restrict__ acc,
                             const int* __restrict__ valid,
                             float* __restrict__ out) {
  float l = 0.f;
  if (valid[0] > 0) l += acc[0] / (float)(BATCH * valid[0]);
  if (valid[1] > 0) l += acc[1] / (float)(BATCH * valid[1]);
  out[0] = l;
}

extern "C" void kernel_launch(void* const* d_in, const int* in_sizes, int n_in,
                              void* d_out, int out_size, void* d_ws,
                              size_t ws_size, hipStream_t stream) {
  const float* x0 = (const float*)d_in[0];
  const float* x1 = (const float*)d_in[1];
  const float* w0 = (const float*)d_in[2];
  const float* w1 = (const float*)d_in[3];
  const float* ehy0 = (const float*)d_in[4];
  const float* ehy1 = (const float*)d_in[5];
  const float* enod0 = (const float*)d_in[6];
  const float* enod1 = (const float*)d_in[7];

  float* out = (float*)d_out;
  float* adj0 = out;                       // 640*128
  float* adj1 = out + 640 * 128;           // 384*64
  float* lossp = out + 640 * 128 + 384 * 64;

  unsigned short* nhat0 = (unsigned short*)d_ws;
  unsigned short* nhat1 = nhat0 + (size_t)BATCH * 640 * DDIM;
  int* ip = (int*)(nhat1 + (size_t)BATCH * 384 * DDIM);
  int* labels0 = ip;
  int* labels1 = labels0 + 640;
  int* cnt0 = labels1 + 384;
  int* cnt1 = cnt0 + 640;
  int* valid = cnt1 + 384;
  float* acc = (float*)(valid + 2);

  adj_kernel<<<1024, 128, 0, stream>>>(enod0, ehy0, enod1, ehy1, adj0, adj1,
                                       labels0, labels1, acc);
  cnt_kernel<<<2, 256, 0, stream>>>(labels0, cnt0, labels1, cnt1, valid);
  normalize_kernel<<<BATCH * (640 + 384), 128, 0, stream>>>(x0, w0, x1, w1,
                                                            nhat0, nhat1);
  lse_kernel<<<1024, 256, 0, stream>>>(nhat0, labels0, cnt0, nhat1, labels1,
                                       cnt1, acc);
  final_kernel<<<1, 1, 0, stream>>>(acc, valid, lossp);
}

// Round 8
// 246.764 us; speedup vs baseline: 3.8852x; 1.0703x over previous
//
#include <hip/hip_runtime.h>

// incidence_matrix_learn on MI355X — round 8.
// Round-7 post-mortem: lse is LDS-read-bound: 4 waves re-read each staged
// B-frag -> 64 KB LDS reads per 16 KB chunk = 2.6 GB aggregate = ~26 TB/s
// (~50% of LDS ceiling), MfmaUtil 14%. Fix (a): wave holds 32 A-rows (two
// 16-row frag sets, 128 VGPRs), block = 2 waves/128 thr on a 64-row n-tile ->
// each B-frag feeds 2 MFMAs, LDS reads per MAC halved. (b) normalize -> one
// wave per row, no LDS/sync. (c) adj fused into the normalize launch.
// Validated algebra (rounds 1-7, absmax 0.0): top-k no-op; P via labels;
// fixed-shift-10 LSE; bf16 nhat; cnt = label-histogram - 1.

#define DDIM 512
#define BATCH 64

typedef __attribute__((ext_vector_type(8))) short short8;
typedef __attribute__((ext_vector_type(4))) float f32x4;

__device__ __forceinline__ unsigned short f2bf(float f) {
  unsigned int u = __float_as_uint(f);
  u += 0x7fffu + ((u >> 16) & 1u);   // RNE
  return (unsigned short)(u >> 16);
}

__device__ __forceinline__ void async16(const void* g, void* l) {
  __builtin_amdgcn_global_load_lds(
      (const __attribute__((address_space(1))) unsigned int*)g,
      (__attribute__((address_space(3))) unsigned int*)l, 16, 0, 0);
}

// Fused prep kernel, 256 threads. Blocks [0,1024): adj (both scales) + acc
// init. Blocks [1024, 1024+16384): normalize, one WAVE per node row.
__global__ __launch_bounds__(256) void prep_kernel(
    const float* __restrict__ enod0, const float* __restrict__ ehy0,
    const float* __restrict__ enod1, const float* __restrict__ ehy1,
    float* __restrict__ adj0, float* __restrict__ adj1,
    int* __restrict__ labels0, int* __restrict__ labels1,
    const float* __restrict__ x0, const float* __restrict__ w0,
    const float* __restrict__ x1, const float* __restrict__ w1,
    unsigned short* __restrict__ nhat0, unsigned short* __restrict__ nhat1,
    float* __restrict__ acc) {
  const int t = threadIdx.x;
  if (blockIdx.x < 1024) {
    // ---- adj path ----
    if (blockIdx.x == 0 && t == 0) { acc[0] = 0.f; acc[1] = 0.f; }
    const bool s0 = blockIdx.x < 640;
    const int n = s0 ? blockIdx.x : blockIdx.x - 640;
    const int H = s0 ? 128 : 64;
    const float* enod = s0 ? enod0 : enod1;
    const float* ehy = s0 ? ehy0 : ehy1;
    float* out_adj = s0 ? adj0 : adj1;
    int* labels = s0 ? labels0 : labels1;
    __shared__ float erow[DDIM];
    __shared__ float red[128];
    __shared__ int lab;
    if (t < 128) ((float4*)erow)[t] = ((const float4*)(enod + (size_t)n * DDIM))[t];
    if (t == 0) lab = -1;
    __syncthreads();
    float v = 0.f;
    if (t < H) {
      const float4* hr = (const float4*)(ehy + (size_t)t * DDIM);
      float a = 0.f;
      #pragma unroll 8
      for (int d = 0; d < DDIM / 4; ++d) {
        float4 h = hr[d];
        float4 e = ((const float4*)erow)[d];
        a = fmaf(h.x, e.x, a); a = fmaf(h.y, e.y, a);
        a = fmaf(h.z, e.z, a); a = fmaf(h.w, e.w, a);
      }
      v = fmaxf(0.f, 3.0f * a);
    }
    if (t < 128) red[t] = v;
    __syncthreads();
    for (int s = 64; s > 0; s >>= 1) {
      if (t < s) red[t] = fmaxf(red[t], red[t + s]);
      __syncthreads();
    }
    const float mx = red[0];
    __syncthreads();
    const float e = (t < H) ? __expf(v - mx) : 0.f;
    if (t < 128) red[t] = e;
    __syncthreads();
    for (int s = 64; s > 0; s >>= 1) {
      if (t < s) red[t] += red[t + s];
      __syncthreads();
    }
    const float sum = red[0];
    if (t < H) {
      const float adj = e / sum;
      const float bin = (adj > 0.5f) ? 1.0f : 0.0f;
      out_adj[(size_t)n * H + t] = bin;
      if (bin > 0.f) lab = t;
    }
    __syncthreads();
    if (t == 0) labels[n] = lab;
  } else {
    // ---- normalize path: wave per row ----
    const int wave = t >> 6;
    const int lane = t & 63;
    const int g = (blockIdx.x - 1024) * 4 + wave;   // global row id, < 65536
    const bool s0 = g < BATCH * 640;
    const int gg = s0 ? g : g - BATCH * 640;
    const int N = s0 ? 640 : 384;
    const int L = s0 ? 512 : 256;
    const float* x = s0 ? x0 : x1;
    const float* w = s0 ? w0 : w1;
    unsigned short* nhat = s0 ? nhat0 : nhat1;
    const int b = gg / N;
    const int n = gg - b * N;
    const float* src = (n < L) ? (x + ((size_t)b * L + n) * DDIM)
                               : (w + (size_t)(n - L) * DDIM);
    const float4* rowp = (const float4*)src;
    const float4 v0 = rowp[lane];
    const float4 v1 = rowp[lane + 64];
    float ss = v0.x * v0.x + v0.y * v0.y + v0.z * v0.z + v0.w * v0.w +
               v1.x * v1.x + v1.y * v1.y + v1.z * v1.z + v1.w * v1.w;
    #pragma unroll
    for (int off = 32; off > 0; off >>= 1) ss += __shfl_xor(ss, off);
    const float rinv = 1.0f / fmaxf(sqrtf(ss), 1e-12f);
    ushort4 o0, o1;
    o0.x = f2bf(v0.x * rinv); o0.y = f2bf(v0.y * rinv);
    o0.z = f2bf(v0.z * rinv); o0.w = f2bf(v0.w * rinv);
    o1.x = f2bf(v1.x * rinv); o1.y = f2bf(v1.y * rinv);
    o1.z = f2bf(v1.z * rinv); o1.w = f2bf(v1.w * rinv);
    ushort4* op = (ushort4*)(nhat + ((size_t)b * N + n) * DDIM);
    op[lane] = o0;
    op[lane + 64] = o1;
  }
}

// 2 blocks. cnt[i] = hist[lab[i]] - 1 via 128-bin LDS label histogram.
__global__ __launch_bounds__(256) void cnt_kernel(
    const int* __restrict__ labels0, int* __restrict__ cnt0,
    const int* __restrict__ labels1, int* __restrict__ cnt1,
    int* __restrict__ valid) {
  const bool s0 = blockIdx.x == 0;
  const int* labels = s0 ? labels0 : labels1;
  int* cnt = s0 ? cnt0 : cnt1;
  int* validcnt = s0 ? valid : valid + 1;
  const int N = s0 ? 640 : 384;
  __shared__ int lab[640];
  __shared__ int hist[128];
  __shared__ int vc;
  const int t = threadIdx.x;
  if (t == 0) vc = 0;
  if (t < 128) hist[t] = 0;
  for (int i = t; i < N; i += 256) lab[i] = labels[i];
  __syncthreads();
  for (int i = t; i < N; i += 256)
    if (lab[i] >= 0) atomicAdd(&hist[lab[i]], 1);
  __syncthreads();
  int lv = 0;
  for (int i = t; i < N; i += 256) {
    const int c = (lab[i] >= 0) ? hist[lab[i]] - 1 : 0;
    cnt[i] = c;
    if (c > 0) ++lv;
  }
  if (lv > 0) atomicAdd(&vc, lv);
  __syncthreads();
  if (t == 0) *validcnt = vc;
}

// Pipelined MFMA lse kernel, 128 threads (2 waves) per 64-row n-tile.
// Each wave holds 32 A-rows as TWO 16-row fragment sets (a0/a1, 128 VGPRs,
// full K=512) -> each staged B-frag read feeds 2 MFMAs (LDS reads per MAC
// halved vs round 7). B staged to double-buffered frag-order LDS chunks
// (64 m x 128 k = 16 frags), prefetched one chunk ahead, 8 frags per wave.
// kc fully unrolled so register indices + buffer parity are compile-time.
__global__ __launch_bounds__(128, 2) void lse_kernel(
    const unsigned short* __restrict__ nhat0, const int* __restrict__ labels0,
    const int* __restrict__ cnt0, const unsigned short* __restrict__ nhat1,
    const int* __restrict__ labels1, const int* __restrict__ cnt1,
    float* __restrict__ loss_acc) {
  __shared__ short8 Bbuf[2][1024];   // 2 x 16 KB, frag-order
  __shared__ int labS[640];
  __shared__ float redS[64];
  __shared__ float redP[64];
  const int tid = threadIdx.x;
  const bool s0 = blockIdx.x < 640;
  const int i = s0 ? blockIdx.x : blockIdx.x - 640;
  const int N = s0 ? 640 : 384;
  const int ntiles = s0 ? 10 : 6;
  const unsigned short* nhat = s0 ? nhat0 : nhat1;
  const int* labels = s0 ? labels0 : labels1;
  const int* cnt = s0 ? cnt0 : cnt1;
  float* acc_out = s0 ? loss_acc : loss_acc + 1;
  const int b = i & 63;        // XCD swizzle: batch fixes XCD residue
  const int tn = i >> 6;
  const int n0 = tn * 64;
  const int wave = tid >> 6;   // 0..1
  const int lane = tid & 63;
  const int lrow = lane & 15;   // A-row within 16 / B-col / C-col
  const int lq = lane >> 4;     // k-chunk selector / C row group
  for (int t = tid; t < N; t += 128) labS[t] = labels[t];

  const size_t base = (size_t)b * N * DDIM;
  const int rw0 = n0 + wave * 32;   // wave owns rows rw0 .. rw0+31
  const unsigned short* Ap0 = nhat + base + (size_t)(rw0 + lrow) * DDIM + lq * 8;
  const unsigned short* Ap1 = nhat + base + (size_t)(rw0 + 16 + lrow) * DDIM + lq * 8;
  short8 a0[16], a1[16];
  #pragma unroll
  for (int ks = 0; ks < 16; ++ks) {
    a0[ks] = *(const short8*)(Ap0 + ks * 32);
    a1[ks] = *(const short8*)(Ap1 + ks * 32);
  }

  // stage chunk 0 (mt=0, kc=0): this wave's 8 frags f = wave*8 .. +7
  const int f0 = wave * 8;
  #pragma unroll
  for (int fi = 0; fi < 8; ++fi) {
    const int f = f0 + fi;
    const int j = f >> 2, ks = f & 3;
    const unsigned short* g = nhat + base +
        (size_t)(j * 16 + lrow) * DDIM + ks * 32 + lq * 8;
    async16(g, &Bbuf[0][f * 64]);
  }
  __syncthreads();   // drains staging (vmcnt) + labS writes

  int labn[2][4];
  #pragma unroll
  for (int s = 0; s < 2; ++s)
    #pragma unroll
    for (int r = 0; r < 4; ++r) labn[s][r] = labS[rw0 + s * 16 + lq * 4 + r];

  float se[2][4] = {{0.f, 0.f, 0.f, 0.f}, {0.f, 0.f, 0.f, 0.f}};
  float pos[2][4] = {{0.f, 0.f, 0.f, 0.f}, {0.f, 0.f, 0.f, 0.f}};
  const int nchunks = ntiles * 4;

  for (int mt = 0; mt < ntiles; ++mt) {
    f32x4 acc[4][2];
    #pragma unroll
    for (int j = 0; j < 4; ++j) {
      acc[j][0] = (f32x4){0.f, 0.f, 0.f, 0.f};
      acc[j][1] = (f32x4){0.f, 0.f, 0.f, 0.f};
    }
    #pragma unroll
    for (int kc = 0; kc < 4; ++kc) {
      // prefetch chunk (mt*4 + kc + 1) into buffer parity (kc+1)&1
      const int nc = mt * 4 + kc + 1;
      if (nc < nchunks) {
        const int mt2 = nc >> 2, kc2 = nc & 3;
        short8* dst = &Bbuf[(kc + 1) & 1][0];
        #pragma unroll
        for (int fi = 0; fi < 8; ++fi) {
          const int f = f0 + fi;
          const int j = f >> 2, ks = f & 3;
          const unsigned short* g = nhat + base +
              (size_t)(mt2 * 64 + j * 16 + lrow) * DDIM +
              kc2 * 128 + ks * 32 + lq * 8;
          async16(g, dst + f * 64);
        }
      }
      // compute chunk kc from Bbuf[kc&1]; all register indices compile-time
      const short8* bb = &Bbuf[kc & 1][0];
      #pragma unroll
      for (int ks = 0; ks < 4; ++ks) {
        const short8 b0 = bb[(0 + ks) * 64 + lane];
        const short8 b1 = bb[(4 + ks) * 64 + lane];
        const short8 b2 = bb[(8 + ks) * 64 + lane];
        const short8 b3 = bb[(12 + ks) * 64 + lane];
        const short8 av0 = a0[kc * 4 + ks];
        const short8 av1 = a1[kc * 4 + ks];
        acc[0][0] = __builtin_amdgcn_mfma_f32_16x16x32_bf16(av0, b0, acc[0][0], 0, 0, 0);
        acc[0][1] = __builtin_amdgcn_mfma_f32_16x16x32_bf16(av1, b0, acc[0][1], 0, 0, 0);
        acc[1][0] = __builtin_amdgcn_mfma_f32_16x16x32_bf16(av0, b1, acc[1][0], 0, 0, 0);
        acc[1][1] = __builtin_amdgcn_mfma_f32_16x16x32_bf16(av1, b1, acc[1][1], 0, 0, 0);
        acc[2][0] = __builtin_amdgcn_mfma_f32_16x16x32_bf16(av0, b2, acc[2][0], 0, 0, 0);
        acc[2][1] = __builtin_amdgcn_mfma_f32_16x16x32_bf16(av1, b2, acc[2][1], 0, 0, 0);
        acc[3][0] = __builtin_amdgcn_mfma_f32_16x16x32_bf16(av0, b3, acc[3][0], 0, 0, 0);
        acc[3][1] = __builtin_amdgcn_mfma_f32_16x16x32_bf16(av1, b3, acc[3][1], 0, 0, 0);
      }
      __syncthreads();   // staging for nc drained; buffer swap safe
    }
    // epilogue for this m-tile
    const int m0 = mt * 64;
    #pragma unroll
    for (int j = 0; j < 4; ++j) {
      const int m = m0 + j * 16 + lrow;
      const int labm = labS[m];
      #pragma unroll
      for (int s = 0; s < 2; ++s) {
        const int row0 = rw0 + s * 16 + lq * 4;
        #pragma unroll
        for (int r = 0; r < 4; ++r) {
          const float sim = acc[j][s][r] * 10.0f;    // 1/TAU
          se[s][r] += __expf(sim - 10.0f);           // fixed shift (diag max)
          if (labn[s][r] >= 0 && labm == labn[s][r] && m != row0 + r)
            pos[s][r] += sim;
        }
      }
    }
  }

  // reduce across the 16 col-lanes of each row group
  #pragma unroll
  for (int off = 1; off <= 8; off <<= 1) {
    #pragma unroll
    for (int s = 0; s < 2; ++s)
      #pragma unroll
      for (int r = 0; r < 4; ++r) {
        se[s][r] += __shfl_xor(se[s][r], off);
        pos[s][r] += __shfl_xor(pos[s][r], off);
      }
  }
  if (lrow == 0) {
    #pragma unroll
    for (int s = 0; s < 2; ++s)
      #pragma unroll
      for (int r = 0; r < 4; ++r) {
        redS[wave * 32 + s * 16 + lq * 4 + r] = se[s][r];
        redP[wave * 32 + s * 16 + lq * 4 + r] = pos[s][r];
      }
  }
  __syncthreads();
  if (tid < 64) {
    const int c = cnt[n0 + tid];
    if (c > 0)
      atomicAdd(acc_out, (10.0f + logf(redS[tid])) - redP[tid] / (float)c);
  }
}

__global__ void final_kernel(const float* __restrict__ acc,
                             const int* __restrict__ valid,
                             float* __restrict__ out) {
  float l = 0.f;
  if (valid[0] > 0) l += acc[0] / (float)(BATCH * valid[0]);
  if (valid[1] > 0) l += acc[1] / (float)(BATCH * valid[1]);
  out[0] = l;
}

extern "C" void kernel_launch(void* const* d_in, const int* in_sizes, int n_in,
                              void* d_out, int out_size, void* d_ws,
                              size_t ws_size, hipStream_t stream) {
  const float* x0 = (const float*)d_in[0];
  const float* x1 = (const float*)d_in[1];
  const float* w0 = (const float*)d_in[2];
  const float* w1 = (const float*)d_in[3];
  const float* ehy0 = (const float*)d_in[4];
  const float* ehy1 = (const float*)d_in[5];
  const float* enod0 = (const float*)d_in[6];
  const float* enod1 = (const float*)d_in[7];

  float* out = (float*)d_out;
  float* adj0 = out;                       // 640*128
  float* adj1 = out + 640 * 128;           // 384*64
  float* lossp = out + 640 * 128 + 384 * 64;

  unsigned short* nhat0 = (unsigned short*)d_ws;
  unsigned short* nhat1 = nhat0 + (size_t)BATCH * 640 * DDIM;
  int* ip = (int*)(nhat1 + (size_t)BATCH * 384 * DDIM);
  int* labels0 = ip;
  int* labels1 = labels0 + 640;
  int* cnt0 = labels1 + 384;
  int* cnt1 = cnt0 + 640;
  int* valid = cnt1 + 384;
  float* acc = (float*)(valid + 2);

  prep_kernel<<<1024 + 16384, 256, 0, stream>>>(
      enod0, ehy0, enod1, ehy1, adj0, adj1, labels0, labels1,
      x0, w0, x1, w1, nhat0, nhat1, acc);
  cnt_kernel<<<2, 256, 0, stream>>>(labels0, cnt0, labels1, cnt1, valid);
  lse_kernel<<<1024, 128, 0, stream>>>(nhat0, labels0, cnt0, nhat1, labels1,
                                       cnt1, acc);
  final_kernel<<<1, 1, 0, stream>>>(acc, valid, lossp);
}